// Round 3
// baseline (606.496 us; speedup 1.0000x reference)
//
#include <hip/hip_runtime.h>

#define BATCH 256
#define SEQ_T 512
#define CIN   6
#define RES   256

// fmac with SGPR broadcast (h) * VGPR (w): forces W into arch VGPRs at use.
#define FMAC_SV(acc, s_h, v_w) \
    asm("v_fmac_f32 %0, %1, %2" : "+v"(acc) : "s"(s_h), "v"(v_w))

// 512 threads (8 waves) per block, one block per batch row (grid=256 -> 1/CU).
// Phase 1: wave w owns k-chunk [32w, 32w+32); lane g owns cols {4g..4g+3}.
//   W slice = 32 x float4 = 128 VGPRs, truly register-resident
//   (__launch_bounds__(512,2) grants 256 unified regs/thread).
//   h chunk is wave-uniform: one ds_read_b32 + readlane j -> SGPR broadcast.
// Phase 2 (tid<256): col c = tid; sum 8 partials + x@W_in, tanh, write.
__global__ __launch_bounds__(512, 2)
void esn_scan_kernel(const float* __restrict__ x,
                     const float* __restrict__ W_in,
                     const float* __restrict__ W_res,
                     float* __restrict__ out) {
    __shared__ float h[2][RES];
    __shared__ float part[8][RES];

    const int tid  = threadIdx.x;
    const int b    = blockIdx.x;
    const int w    = tid >> 6;        // wave id 0..7 -> k-chunk [32w, 32w+32)
    const int g    = tid & 63;        // lane -> col block {4g..4g+3}
    const int lane = tid & 31;

    // W slice: wv[j] = W[32w+j][4g..4g+3]; consecutive lanes -> consecutive
    // float4s (perfectly coalesced).
    float4 wv[32];
    #pragma unroll
    for (int j = 0; j < 32; ++j)
        wv[j] = ((const float4*)W_res)[(32 * w + j) * 64 + g];

    float win[CIN];
    if (tid < RES) {
        #pragma unroll
        for (int c = 0; c < CIN; ++c) win[c] = W_in[c * RES + tid];
    }

    if (tid < RES) h[0][tid] = 0.0f;
    __syncthreads();

    const float* xb = x + (size_t)b * SEQ_T * CIN;
    float*       ob = out + (size_t)b * SEQ_T * RES;

    int p = 0;
    for (int t = 0; t < SEQ_T; ++t) {
        // Uniform x load (s_load; consumed in phase 2 after the barrier).
        float xv[CIN];
        #pragma unroll
        for (int c = 0; c < CIN; ++c) xv[c] = xb[t * CIN + c];

        // Phase 1: matvec partials, pure v_fmac stream (no LDS in loop).
        float hv = h[p][32 * w + lane];
        float a0 = 0.0f, a1 = 0.0f, a2 = 0.0f, a3 = 0.0f;
        #pragma unroll
        for (int j = 0; j < 32; ++j) {
            const float hj = __int_as_float(
                __builtin_amdgcn_readlane(__float_as_int(hv), j));
            FMAC_SV(a0, hj, wv[j].x);
            FMAC_SV(a1, hj, wv[j].y);
            FMAC_SV(a2, hj, wv[j].z);
            FMAC_SV(a3, hj, wv[j].w);
        }
        ((float4*)&part[w][0])[g] = make_float4(a0, a1, a2, a3);
        __syncthreads();

        // Phase 2: reduce 8 partials + input projection + tanh + writes.
        if (tid < RES) {
            float s = 0.0f;
            #pragma unroll
            for (int c = 0; c < CIN; ++c) s = fmaf(xv[c], win[c], s);
            #pragma unroll
            for (int q = 0; q < 8; ++q) s += part[q][tid];
            float e  = __expf(2.0f * s);
            float hn = 1.0f - 2.0f * __builtin_amdgcn_rcpf(e + 1.0f);
            h[1 - p][tid]     = hn;
            ob[t * RES + tid] = hn;
        }
        __syncthreads();
        p ^= 1;
    }
}

extern "C" void kernel_launch(void* const* d_in, const int* in_sizes, int n_in,
                              void* d_out, int out_size, void* d_ws, size_t ws_size,
                              hipStream_t stream) {
    const float* x     = (const float*)d_in[0];
    const float* W_in  = (const float*)d_in[1];
    const float* W_res = (const float*)d_in[2];
    float*       out   = (float*)d_out;

    esn_scan_kernel<<<BATCH, 512, 0, stream>>>(x, W_in, W_res, out);
}